// Round 1
// baseline (4695.650 us; speedup 1.0000x reference)
//
#include <hip/hip_runtime.h>
#include <hip/hip_bf16.h>

#define B_ 2048
#define EPSF 1e-5f

// ---------------- lin_w transpose: (2,512,256) -> (2,256,512) ----------------
__global__ __launch_bounds__(256) void k_transpose(const float* __restrict__ w,
                                                   float* __restrict__ wT) {
  int idx = blockIdx.x * 256 + threadIdx.x;          // 2*512*256 = 262144
  if (idx >= 2 * 512 * 256) return;
  int l = idx >> 17;
  int r = idx & 131071;
  int m = r >> 8;          // 0..511
  int d = r & 255;         // 0..255
  wT[l * 131072 + d * 512 + m] = w[idx];
}

// ---------------- shared helper: LN over 512 + to_patches into LDS ----------
__device__ __forceinline__ void ln_to_patches(const float* __restrict__ xb,
                                              const float* __restrict__ g,
                                              const float* __restrict__ beta,
                                              float (*p)[257], int tid) {
  int lane = tid & 63, wave = tid >> 6;
  for (int r = wave; r < 16; r += 4) {
    float vals[8];
    float s = 0.f, ss = 0.f;
#pragma unroll
    for (int j = 0; j < 8; j++) {
      float t = xb[r * 512 + lane + j * 64];
      vals[j] = t; s += t; ss += t * t;
    }
#pragma unroll
    for (int o = 32; o; o >>= 1) { s += __shfl_xor(s, o); ss += __shfl_xor(ss, o); }
    float m = s * (1.f / 512.f);
    float inv = rsqrtf(ss * (1.f / 512.f) - m * m + EPSF);
#pragma unroll
    for (int j = 0; j < 8; j++) {
      int col = lane + j * 64;
      p[col >> 4][r * 16 + (col & 15)] = (vals[j] - m) * inv * g[col] + beta[col];
    }
  }
}

// ---------------- K1: LN1 + patches + qkv (dw3x3 s2 + BN + pw 32x32) --------
__global__ __launch_bounds__(256) void k_qkv(
    const float* __restrict__ x, const float* __restrict__ g,
    const float* __restrict__ beta, const float* __restrict__ dw,
    const float* __restrict__ bng, const float* __restrict__ bnb,
    const float* __restrict__ bnm, const float* __restrict__ bnv,
    const float* __restrict__ pw, float* __restrict__ qout,
    float* __restrict__ kout, float* __restrict__ vout) {
  __shared__ float p[32][257];
  __shared__ float dwo[32][64];
  int b = blockIdx.x, tid = threadIdx.x;
  ln_to_patches(x + (size_t)b * 8192, g, beta, p, tid);
  __syncthreads();
  for (int i = 0; i < 3; i++) {
    const float* dwi = dw + i * 288;   // 32*9
    const float* pwi = pw + i * 1024;  // 32*32
#pragma unroll
    for (int j = 0; j < 8; j++) {
      int idx = tid + j * 256;
      int c = idx >> 6, pos = idx & 63;
      int oy = pos >> 3, ox = pos & 7;
      float acc = 0.f;
#pragma unroll
      for (int ky = 0; ky < 3; ky++) {
        int iy = 2 * oy + ky - 1;
        if (iy < 0 || iy > 15) continue;
#pragma unroll
        for (int kx = 0; kx < 3; kx++) {
          int ix = 2 * ox + kx - 1;
          if (ix < 0 || ix > 15) continue;
          acc += dwi[c * 9 + ky * 3 + kx] * p[c][iy * 16 + ix];
        }
      }
      float scale = bng[i * 32 + c] * rsqrtf(bnv[i * 32 + c] + EPSF);
      dwo[c][pos] = (acc - bnm[i * 32 + c]) * scale + bnb[i * 32 + c];
    }
    __syncthreads();
    float* out = (i == 0) ? qout : (i == 1) ? kout : vout;
#pragma unroll
    for (int j = 0; j < 8; j++) {
      int idx = tid + j * 256;
      int o = idx >> 6, pos = idx & 63;
      float acc = 0.f;
#pragma unroll
      for (int c = 0; c < 32; c++) acc += pwi[o * 32 + c] * dwo[c][pos];
      out[(size_t)b * 2048 + idx] = acc;
    }
    __syncthreads();
  }
}

// ---------------- K2: attention + reorder + c1d ------------------------------
__global__ __launch_bounds__(256) void k_attn(
    const float* __restrict__ q, const float* __restrict__ k,
    const float* __restrict__ v, const float* __restrict__ pos,
    const float* __restrict__ c1w, const float* __restrict__ c1b,
    float* __restrict__ xc) {
  __shared__ float qs[32][65], ks[32][65], vs[32][65];
  __shared__ float sc[32][33];
  __shared__ float os[32][65];
  int b = blockIdx.x, tid = threadIdx.x;
  size_t base = (size_t)b * 2048;
#pragma unroll
  for (int j = 0; j < 8; j++) {
    int idx = tid + j * 256;
    int d = idx >> 6, e = idx & 63;
    qs[d][e] = q[base + idx];
    ks[d][e] = k[base + idx];
    vs[d][e] = v[base + idx];
  }
  __syncthreads();
#pragma unroll
  for (int j = 0; j < 4; j++) {
    int idx = tid + j * 256;
    int d = idx >> 5, f = idx & 31;
    float acc = 0.f;
#pragma unroll
    for (int e = 0; e < 64; e++) acc += qs[d][e] * ks[f][e];
    sc[d][f] = acc * 0.125f + pos[d * 32 + f];
  }
  __syncthreads();
  if (tid < 32) {
    float mx = -1e30f;
#pragma unroll
    for (int f = 0; f < 32; f++) mx = fmaxf(mx, sc[tid][f]);
    float s = 0.f;
#pragma unroll
    for (int f = 0; f < 32; f++) { float e = __expf(sc[tid][f] - mx); sc[tid][f] = e; s += e; }
    float inv = 1.f / s;
#pragma unroll
    for (int f = 0; f < 32; f++) sc[tid][f] *= inv;
  }
  __syncthreads();
#pragma unroll
  for (int j = 0; j < 8; j++) {
    int idx = tid + j * 256;
    int d = idx >> 6, e = idx & 63;
    float acc = 0.f;
#pragma unroll
    for (int f = 0; f < 32; f++) acc += sc[d][f] * vs[f][e];
    os[d][e] = acc;
  }
  __syncthreads();
  // xc[u][dd*8+p2] = sum_c c1w[u][c] * os[dd][c*8+p2] + c1b[u]
#pragma unroll
  for (int j = 0; j < 16; j++) {
    int idx = tid + j * 256;          // 0..4095
    int u = idx >> 8, jj = idx & 255;
    int dd = jj >> 3, p2 = jj & 7;
    float acc = c1b[u];
#pragma unroll
    for (int c = 0; c < 8; c++) acc += c1w[u * 8 + c] * os[dd][c * 8 + p2];
    xc[(size_t)b * 4096 + idx] = acc;
  }
}

// ---------------- K3: lin (16x512 <- 16x256 @ 256x512) + residual ------------
__global__ __launch_bounds__(256) void k_lin(
    const float* __restrict__ xc, const float* __restrict__ wT,
    const float* __restrict__ bias, float* __restrict__ x) {
  __shared__ float xcl[16][256];
  int b = blockIdx.x, tid = threadIdx.x;
#pragma unroll
  for (int j = 0; j < 16; j++) {
    int idx = tid + j * 256;
    xcl[idx >> 8][idx & 255] = xc[(size_t)b * 4096 + idx];
  }
  __syncthreads();
  float acc0[16], acc1[16];
#pragma unroll
  for (int u = 0; u < 16; u++) { acc0[u] = 0.f; acc1[u] = 0.f; }
  int m0 = tid, m1 = tid + 256;
  for (int d = 0; d < 256; d++) {
    float w0 = wT[d * 512 + m0];
    float w1 = wT[d * 512 + m1];
#pragma unroll
    for (int u = 0; u < 16; u++) {
      float xv = xcl[u][d];
      acc0[u] += xv * w0;
      acc1[u] += xv * w1;
    }
  }
  float b0 = bias[m0], b1 = bias[m1];
  float* xb = x + (size_t)b * 8192;
#pragma unroll
  for (int u = 0; u < 16; u++) {
    xb[u * 512 + m0] += acc0[u] + b0;
    xb[u * 512 + m1] += acc1[u] + b1;
  }
}

// ---------------- K4: LN2 + patches + f1 + ReLU -> y1 (bf16) -----------------
__global__ __launch_bounds__(256) void k_f1(
    const float* __restrict__ x, const float* __restrict__ g,
    const float* __restrict__ beta, const float* __restrict__ f1w,
    const float* __restrict__ f1b, __hip_bfloat16* __restrict__ y1) {
  __shared__ float p[32][257];
  int b = blockIdx.x, tid = threadIdx.x;
  ln_to_patches(x + (size_t)b * 8192, g, beta, p, tid);
  __syncthreads();
  int pos = tid;  // 0..255
  __hip_bfloat16* out = y1 + (size_t)b * 32768;
  for (int o = 0; o < 128; o++) {
    float acc = f1b[o];
#pragma unroll
    for (int c = 0; c < 32; c++) acc += f1w[o * 32 + c] * p[c][pos];
    out[o * 256 + pos] = __float2bfloat16(fmaxf(acc, 0.f));
  }
}

// ---------------- K5: dw3x3 s1 + bias + BN + fpw + ReLU + f2 + residual ------
__global__ __launch_bounds__(512) void k_ffn(
    const __hip_bfloat16* __restrict__ y1g, const float* __restrict__ dww,
    const float* __restrict__ dwb, const float* __restrict__ bng,
    const float* __restrict__ bnb, const float* __restrict__ bnm,
    const float* __restrict__ bnv, const float* __restrict__ pww,
    const float* __restrict__ pwb, const float* __restrict__ f2w,
    const float* __restrict__ f2b, float* __restrict__ x) {
  __shared__ __align__(16) __hip_bfloat16 bufA[128][256];  // y1; reused as fp32 partial
  __shared__ __align__(16) __hip_bfloat16 bufB[128][256];  // t
  int b = blockIdx.x, tid = threadIdx.x;
  const __hip_bfloat16* y1b = y1g + (size_t)b * 32768;
#pragma unroll
  for (int j = 0; j < 64; j++) {
    int idx = tid + j * 512;
    bufA[idx >> 8][idx & 255] = y1b[idx];
  }
  __syncthreads();
  // depthwise 3x3 stride 1 pad 1 + bias + BN -> bufB (bf16)
  for (int j = 0; j < 64; j++) {
    int idx = tid + j * 512;
    int c = idx >> 8, pos = idx & 255;
    int h = pos >> 4, w = pos & 15;
    float acc = dwb[c];
#pragma unroll
    for (int ky = 0; ky < 3; ky++) {
      int iy = h + ky - 1;
      if (iy < 0 || iy > 15) continue;
#pragma unroll
      for (int kx = 0; kx < 3; kx++) {
        int ix = w + kx - 1;
        if (ix < 0 || ix > 15) continue;
        acc += dww[c * 9 + ky * 3 + kx] * __bfloat162float(bufA[c][iy * 16 + ix]);
      }
    }
    float scale = bng[c] * rsqrtf(bnv[c] + EPSF);
    bufB[c][pos] = __float2bfloat16((acc - bnm[c]) * scale + bnb[c]);
  }
  __syncthreads();
  // fpw (+bias,ReLU) fused with f2 partial accumulation (no big reg arrays)
  int pos = tid & 255, half = tid >> 8;  // half in {0,1}: o-channels [half*64, half*64+64)
  float part[32];
#pragma unroll
  for (int oc = 0; oc < 32; oc++) part[oc] = 0.f;
  for (int oo = 0; oo < 64; oo++) {
    int o = half * 64 + oo;
    float acc = pwb[o];
#pragma unroll
    for (int c = 0; c < 128; c++) acc += pww[o * 128 + c] * __bfloat162float(bufB[c][pos]);
    acc = fmaxf(acc, 0.f);
#pragma unroll
    for (int oc = 0; oc < 32; oc++) part[oc] += f2w[oc * 128 + o] * acc;
  }
  __syncthreads();  // bufA free (dw stage done for all threads)
  float* partbuf = (float*)&bufA[0][0];  // 2*32*256 fp32 = 64KB
#pragma unroll
  for (int oc = 0; oc < 32; oc++) partbuf[(half * 32 + oc) * 256 + pos] = part[oc];
  __syncthreads();
  float* xb = x + (size_t)b * 8192;
#pragma unroll
  for (int j = 0; j < 16; j++) {
    int idx = tid + j * 512;            // 0..8191
    int d = idx >> 8, pp = idx & 255;
    int p1 = pp >> 4, p2 = pp & 15;
    float val = partbuf[d * 256 + pp] + partbuf[(32 + d) * 256 + pp] + f2b[d];
    xb[p1 * 512 + d * 16 + p2] += val;
  }
}

extern "C" void kernel_launch(void* const* d_in, const int* in_sizes, int n_in,
                              void* d_out, int out_size, void* d_ws, size_t ws_size,
                              hipStream_t stream) {
  const float* x_in   = (const float*)d_in[0];
  const float* ln1_g  = (const float*)d_in[1];
  const float* ln1_b  = (const float*)d_in[2];
  const float* ln2_g  = (const float*)d_in[3];
  const float* ln2_b  = (const float*)d_in[4];
  const float* qkv_dw = (const float*)d_in[5];
  const float* qkv_bng = (const float*)d_in[6];
  const float* qkv_bnb = (const float*)d_in[7];
  const float* qkv_bnm = (const float*)d_in[8];
  const float* qkv_bnv = (const float*)d_in[9];
  const float* qkv_pw = (const float*)d_in[10];
  const float* position = (const float*)d_in[11];
  const float* c1d_w  = (const float*)d_in[12];
  const float* c1d_b  = (const float*)d_in[13];
  const float* lin_w  = (const float*)d_in[14];
  const float* lin_b  = (const float*)d_in[15];
  const float* f1_w   = (const float*)d_in[16];
  const float* f1_b   = (const float*)d_in[17];
  const float* fdw_w  = (const float*)d_in[18];
  const float* fdw_b  = (const float*)d_in[19];
  const float* f_bng  = (const float*)d_in[20];
  const float* f_bnb  = (const float*)d_in[21];
  const float* f_bnm  = (const float*)d_in[22];
  const float* f_bnv  = (const float*)d_in[23];
  const float* fpw_w  = (const float*)d_in[24];
  const float* fpw_b  = (const float*)d_in[25];
  const float* f2_w   = (const float*)d_in[26];
  const float* f2_b   = (const float*)d_in[27];

  float* xbuf = (float*)d_out;                       // running x lives in d_out
  float* q  = (float*)d_ws;                          // (B,32,64)
  float* k  = q + (size_t)B_ * 2048;
  float* v  = k + (size_t)B_ * 2048;
  float* xc = v + (size_t)B_ * 2048;                 // (B,16,256)
  float* wT = xc + (size_t)B_ * 4096;                // (2,256,512)
  __hip_bfloat16* y1 = (__hip_bfloat16*)(wT + 2 * 131072);  // (B,128,256) bf16

  hipMemcpyAsync(xbuf, x_in, (size_t)B_ * 8192 * sizeof(float),
                 hipMemcpyDeviceToDevice, stream);
  k_transpose<<<1024, 256, 0, stream>>>(lin_w, wT);
  for (int l = 0; l < 2; l++) {
    k_qkv<<<B_, 256, 0, stream>>>(xbuf, ln1_g + l * 512, ln1_b + l * 512,
        qkv_dw + l * 864, qkv_bng + l * 96, qkv_bnb + l * 96,
        qkv_bnm + l * 96, qkv_bnv + l * 96, qkv_pw + l * 3072, q, k, v);
    k_attn<<<B_, 256, 0, stream>>>(q, k, v, position + l * 1024,
        c1d_w + l * 128, c1d_b + l * 16, xc);
    k_lin<<<B_, 256, 0, stream>>>(xc, wT + l * 131072, lin_b + l * 512, xbuf);
    k_f1<<<B_, 256, 0, stream>>>(xbuf, ln2_g + l * 512, ln2_b + l * 512,
        f1_w + l * 4096, f1_b + l * 128, y1);
    k_ffn<<<B_, 512, 0, stream>>>(y1, fdw_w + l * 1152, fdw_b + l * 128,
        f_bng + l * 128, f_bnb + l * 128, f_bnm + l * 128, f_bnv + l * 128,
        fpw_w + l * 16384, fpw_b + l * 128, f2_w + l * 4096, f2_b + l * 32, xbuf);
  }
}

// Round 3
// 1878.894 us; speedup vs baseline: 2.4992x; 2.4992x over previous
//
#include <hip/hip_runtime.h>
#include <hip/hip_bf16.h>

#define B_ 2048
#define EPSF 1e-5f

typedef __attribute__((ext_vector_type(8))) short short8v;
typedef __attribute__((ext_vector_type(4))) short short4v;
typedef __attribute__((ext_vector_type(4))) float f32x4;

// float -> bf16 bits, round-to-nearest-even
__device__ __forceinline__ short f2bf_s(float f) {
  union { float f; unsigned u; } v; v.f = f;
  unsigned r = v.u + 0x7fffu + ((v.u >> 16) & 1u);
  return (short)(r >> 16);
}

// ---------------- lin_w transpose: (2,512,256) -> (2,256,512) ----------------
__global__ __launch_bounds__(256) void k_transpose(const float* __restrict__ w,
                                                   float* __restrict__ wT) {
  int idx = blockIdx.x * 256 + threadIdx.x;          // 2*512*256 = 262144
  if (idx >= 2 * 512 * 256) return;
  int l = idx >> 17;
  int r = idx & 131071;
  int m = r >> 8;          // 0..511
  int d = r & 255;         // 0..255
  wT[l * 131072 + d * 512 + m] = w[idx];
}

// ---------------- shared helper: LN over 512 + to_patches into LDS ----------
__device__ __forceinline__ void ln_to_patches(const float* __restrict__ xb,
                                              const float* __restrict__ g,
                                              const float* __restrict__ beta,
                                              float (*p)[257], int tid) {
  int lane = tid & 63, wave = tid >> 6;
  for (int r = wave; r < 16; r += 4) {
    float vals[8];
    float s = 0.f, ss = 0.f;
#pragma unroll
    for (int j = 0; j < 8; j++) {
      float t = xb[r * 512 + lane + j * 64];
      vals[j] = t; s += t; ss += t * t;
    }
#pragma unroll
    for (int o = 32; o; o >>= 1) { s += __shfl_xor(s, o); ss += __shfl_xor(ss, o); }
    float m = s * (1.f / 512.f);
    float inv = rsqrtf(ss * (1.f / 512.f) - m * m + EPSF);
#pragma unroll
    for (int j = 0; j < 8; j++) {
      int col = lane + j * 64;
      p[col >> 4][r * 16 + (col & 15)] = (vals[j] - m) * inv * g[col] + beta[col];
    }
  }
}

// ---------------- K1: LN1 + patches + qkv (dw3x3 s2 + BN + pw 32x32) --------
__global__ __launch_bounds__(256) void k_qkv(
    const float* __restrict__ x, const float* __restrict__ g,
    const float* __restrict__ beta, const float* __restrict__ dw,
    const float* __restrict__ bng, const float* __restrict__ bnb,
    const float* __restrict__ bnm, const float* __restrict__ bnv,
    const float* __restrict__ pw, float* __restrict__ qout,
    float* __restrict__ kout, float* __restrict__ vout) {
  __shared__ float p[32][257];
  __shared__ float dwo[32][64];
  int b = blockIdx.x, tid = threadIdx.x;
  ln_to_patches(x + (size_t)b * 8192, g, beta, p, tid);
  __syncthreads();
  for (int i = 0; i < 3; i++) {
    const float* dwi = dw + i * 288;   // 32*9
    const float* pwi = pw + i * 1024;  // 32*32
#pragma unroll
    for (int j = 0; j < 8; j++) {
      int idx = tid + j * 256;
      int c = idx >> 6, pos = idx & 63;
      int oy = pos >> 3, ox = pos & 7;
      float acc = 0.f;
#pragma unroll
      for (int ky = 0; ky < 3; ky++) {
        int iy = 2 * oy + ky - 1;
        if (iy < 0 || iy > 15) continue;
#pragma unroll
        for (int kx = 0; kx < 3; kx++) {
          int ix = 2 * ox + kx - 1;
          if (ix < 0 || ix > 15) continue;
          acc += dwi[c * 9 + ky * 3 + kx] * p[c][iy * 16 + ix];
        }
      }
      float scale = bng[i * 32 + c] * rsqrtf(bnv[i * 32 + c] + EPSF);
      dwo[c][pos] = (acc - bnm[i * 32 + c]) * scale + bnb[i * 32 + c];
    }
    __syncthreads();
    float* out = (i == 0) ? qout : (i == 1) ? kout : vout;
#pragma unroll
    for (int j = 0; j < 8; j++) {
      int idx = tid + j * 256;
      int o = idx >> 6, pos = idx & 63;
      float acc = 0.f;
#pragma unroll
      for (int c = 0; c < 32; c++) acc += pwi[o * 32 + c] * dwo[c][pos];
      out[(size_t)b * 2048 + idx] = acc;
    }
    __syncthreads();
  }
}

// ---------------- K2: attention + reorder + c1d ------------------------------
__global__ __launch_bounds__(256) void k_attn(
    const float* __restrict__ q, const float* __restrict__ k,
    const float* __restrict__ v, const float* __restrict__ pos,
    const float* __restrict__ c1w, const float* __restrict__ c1b,
    float* __restrict__ xc) {
  __shared__ float qs[32][65], ks[32][65], vs[32][65];
  __shared__ float sc[32][33];
  __shared__ float os[32][65];
  int b = blockIdx.x, tid = threadIdx.x;
  size_t base = (size_t)b * 2048;
#pragma unroll
  for (int j = 0; j < 8; j++) {
    int idx = tid + j * 256;
    int d = idx >> 6, e = idx & 63;
    qs[d][e] = q[base + idx];
    ks[d][e] = k[base + idx];
    vs[d][e] = v[base + idx];
  }
  __syncthreads();
#pragma unroll
  for (int j = 0; j < 4; j++) {
    int idx = tid + j * 256;
    int d = idx >> 5, f = idx & 31;
    float acc = 0.f;
#pragma unroll
    for (int e = 0; e < 64; e++) acc += qs[d][e] * ks[f][e];
    sc[d][f] = acc * 0.125f + pos[d * 32 + f];
  }
  __syncthreads();
  if (tid < 32) {
    float mx = -1e30f;
#pragma unroll
    for (int f = 0; f < 32; f++) mx = fmaxf(mx, sc[tid][f]);
    float s = 0.f;
#pragma unroll
    for (int f = 0; f < 32; f++) { float e = __expf(sc[tid][f] - mx); sc[tid][f] = e; s += e; }
    float inv = 1.f / s;
#pragma unroll
    for (int f = 0; f < 32; f++) sc[tid][f] *= inv;
  }
  __syncthreads();
#pragma unroll
  for (int j = 0; j < 8; j++) {
    int idx = tid + j * 256;
    int d = idx >> 6, e = idx & 63;
    float acc = 0.f;
#pragma unroll
    for (int f = 0; f < 32; f++) acc += sc[d][f] * vs[f][e];
    os[d][e] = acc;
  }
  __syncthreads();
  // xc[u][dd*8+p2] = sum_c c1w[u][c] * os[dd][c*8+p2] + c1b[u]
#pragma unroll
  for (int j = 0; j < 16; j++) {
    int idx = tid + j * 256;          // 0..4095
    int u = idx >> 8, jj = idx & 255;
    int dd = jj >> 3, p2 = jj & 7;
    float acc = c1b[u];
#pragma unroll
    for (int c = 0; c < 8; c++) acc += c1w[u * 8 + c] * os[dd][c * 8 + p2];
    xc[(size_t)b * 4096 + idx] = acc;
  }
}

// ---------------- K3: lin (16x512 <- 16x256 @ 256x512) + residual ------------
__global__ __launch_bounds__(256) void k_lin(
    const float* __restrict__ xc, const float* __restrict__ wT,
    const float* __restrict__ bias, float* __restrict__ x) {
  __shared__ float xcl[16][256];
  int b = blockIdx.x, tid = threadIdx.x;
#pragma unroll
  for (int j = 0; j < 16; j++) {
    int idx = tid + j * 256;
    xcl[idx >> 8][idx & 255] = xc[(size_t)b * 4096 + idx];
  }
  __syncthreads();
  float acc0[16], acc1[16];
#pragma unroll
  for (int u = 0; u < 16; u++) { acc0[u] = 0.f; acc1[u] = 0.f; }
  int m0 = tid, m1 = tid + 256;
  for (int d = 0; d < 256; d++) {
    float w0 = wT[d * 512 + m0];
    float w1 = wT[d * 512 + m1];
#pragma unroll
    for (int u = 0; u < 16; u++) {
      float xv = xcl[u][d];
      acc0[u] += xv * w0;
      acc1[u] += xv * w1;
    }
  }
  float b0 = bias[m0], b1 = bias[m1];
  float* xb = x + (size_t)b * 8192;
#pragma unroll
  for (int u = 0; u < 16; u++) {
    xb[u * 512 + m0] += acc0[u] + b0;
    xb[u * 512 + m1] += acc1[u] + b1;
  }
}

// ---------------- K4: LN2 + patches + f1 + ReLU -> y1 (bf16) -----------------
__global__ __launch_bounds__(256) void k_f1(
    const float* __restrict__ x, const float* __restrict__ g,
    const float* __restrict__ beta, const float* __restrict__ f1w,
    const float* __restrict__ f1b, __hip_bfloat16* __restrict__ y1) {
  __shared__ float p[32][257];
  int b = blockIdx.x, tid = threadIdx.x;
  ln_to_patches(x + (size_t)b * 8192, g, beta, p, tid);
  __syncthreads();
  int pos = tid;  // 0..255
  __hip_bfloat16* out = y1 + (size_t)b * 32768;
  for (int o = 0; o < 128; o++) {
    float acc = f1b[o];
#pragma unroll
    for (int c = 0; c < 32; c++) acc += f1w[o * 32 + c] * p[c][pos];
    out[o * 256 + pos] = __float2bfloat16(fmaxf(acc, 0.f));
  }
}

// ---------------- K5: dw3x3 + BN -> MFMA fpw -> ReLU -> MFMA f2 -> residual --
// LDS plan (135168 B total):
//   region0 (64KB): sY = y1 [128][256] bf16  -> reused: pw_lds[128][136] +
//                   f2w_lds[32][136] bf16    -> reused: f2out[32][257] fp32
//   region1 (68KB): sT [256][136] bf16 ([pos][c], +8 pad) -> reused as
//                   r_lds [pos][o] (fpw output, bf16)
__global__ __launch_bounds__(512) void k_ffn(
    const __hip_bfloat16* __restrict__ y1g, const float* __restrict__ dww,
    const float* __restrict__ dwb, const float* __restrict__ bng,
    const float* __restrict__ bnb, const float* __restrict__ bnm,
    const float* __restrict__ bnv, const float* __restrict__ pww,
    const float* __restrict__ pwb, const float* __restrict__ f2w,
    const float* __restrict__ f2b, float* __restrict__ x) {
  __shared__ __align__(16) __hip_bfloat16 sY[128 * 256];   // 65536 B
  __shared__ __align__(16) __hip_bfloat16 sT[256 * 136];   // 69632 B
  int b = blockIdx.x, tid = threadIdx.x;
  int lane = tid & 63, wid = tid >> 6;
  int row = lane & 15, kg = lane >> 4;

  // ---- stage y1 (vectorized, coalesced) ----
  const uint4* y4 = (const uint4*)(y1g + (size_t)b * 32768);
  uint4* sY4 = (uint4*)sY;
#pragma unroll
  for (int j = 0; j < 8; j++) sY4[tid + j * 512] = y4[tid + j * 512];
  __syncthreads();

  // ---- depthwise 3x3 s1 + bias + BN -> sT[pos][c] bf16 ----
  for (int j = 0; j < 64; j++) {
    int idx = tid + j * 512;
    int c = idx >> 8, pos = idx & 255;
    int h = pos >> 4, w = pos & 15;
    float acc = dwb[c];
#pragma unroll
    for (int ky = 0; ky < 3; ky++) {
      int iy = h + ky - 1;
      if (iy < 0 || iy > 15) continue;
#pragma unroll
      for (int kx = 0; kx < 3; kx++) {
        int ix = w + kx - 1;
        if (ix < 0 || ix > 15) continue;
        acc += dww[c * 9 + ky * 3 + kx] * __bfloat162float(sY[c * 256 + iy * 16 + ix]);
      }
    }
    float scale = bng[c] * rsqrtf(bnv[c] + EPSF);
    sT[pos * 136 + c] = __float2bfloat16((acc - bnm[c]) * scale + bnb[c]);
  }
  __syncthreads();

  // ---- convert weights to bf16 in region0 ----
  __hip_bfloat16* pw_lds = sY;                    // [128][136]
  __hip_bfloat16* f2w_lds = sY + 128 * 136;       // [32][136]
#pragma unroll
  for (int j = 0; j < 32; j++) {
    int idx = tid + j * 512;                      // 16384
    pw_lds[(idx >> 7) * 136 + (idx & 127)] = __float2bfloat16(pww[idx]);
  }
#pragma unroll
  for (int j = 0; j < 8; j++) {
    int idx = tid + j * 512;                      // 4096
    f2w_lds[(idx >> 7) * 136 + (idx & 127)] = __float2bfloat16(f2w[idx]);
  }
  __syncthreads();

  // ---- fpw MFMA: out[o][pos], wave tile 64x64 ----
  int mw = wid & 1, nw = wid >> 1;
  int o0 = mw * 64, pos0 = nw * 64;
  f32x4 acc[4][4] = {};
#pragma unroll
  for (int kk = 0; kk < 4; kk++) {
    int k0 = kk * 32 + kg * 8;
    short8v a[4], bb[4];
#pragma unroll
    for (int mi = 0; mi < 4; mi++)
      a[mi] = *(const short8v*)&pw_lds[(o0 + mi * 16 + row) * 136 + k0];
#pragma unroll
    for (int ni = 0; ni < 4; ni++)
      bb[ni] = *(const short8v*)&sT[(pos0 + ni * 16 + row) * 136 + k0];
#pragma unroll
    for (int mi = 0; mi < 4; mi++)
#pragma unroll
      for (int ni = 0; ni < 4; ni++)
        acc[mi][ni] = __builtin_amdgcn_mfma_f32_16x16x32_bf16(a[mi], bb[ni], acc[mi][ni], 0, 0, 0);
  }
  __syncthreads();  // all waves done reading sT + pw_lds

  // ---- bias + ReLU, write r_lds[pos][o] (overwrites sT) ----
#pragma unroll
  for (int mi = 0; mi < 4; mi++) {
    int obase = o0 + mi * 16 + kg * 4;
    float pb0 = pwb[obase], pb1 = pwb[obase + 1], pb2 = pwb[obase + 2], pb3 = pwb[obase + 3];
#pragma unroll
    for (int ni = 0; ni < 4; ni++) {
      int pos = pos0 + ni * 16 + row;
      short4v pk;
      pk.x = f2bf_s(fmaxf(acc[mi][ni][0] + pb0, 0.f));
      pk.y = f2bf_s(fmaxf(acc[mi][ni][1] + pb1, 0.f));
      pk.z = f2bf_s(fmaxf(acc[mi][ni][2] + pb2, 0.f));
      pk.w = f2bf_s(fmaxf(acc[mi][ni][3] + pb3, 0.f));
      *(short4v*)&sT[pos * 136 + obase] = pk;
    }
  }
  __syncthreads();

  // ---- f2 MFMA: out[d][pos], d=0..31; wave handles 2 n-tiles x 2 m-tiles ----
  f32x4 acc2[2][2] = {};
  int nbase = wid * 2;
#pragma unroll
  for (int kk = 0; kk < 4; kk++) {
    int k0 = kk * 32 + kg * 8;
    short8v a2[2], b2[2];
#pragma unroll
    for (int mi = 0; mi < 2; mi++)
      a2[mi] = *(const short8v*)&f2w_lds[(mi * 16 + row) * 136 + k0];
#pragma unroll
    for (int ni = 0; ni < 2; ni++)
      b2[ni] = *(const short8v*)&sT[((nbase + ni) * 16 + row) * 136 + k0];
#pragma unroll
    for (int mi = 0; mi < 2; mi++)
#pragma unroll
      for (int ni = 0; ni < 2; ni++)
        acc2[mi][ni] = __builtin_amdgcn_mfma_f32_16x16x32_bf16(a2[mi], b2[ni], acc2[mi][ni], 0, 0, 0);
  }
  // f2out (fp32) fits inside the old pw_lds bytes; pw reads finished pre-barrier
  float* f2out = (float*)sY;  // [32][257]
#pragma unroll
  for (int mi = 0; mi < 2; mi++)
#pragma unroll
    for (int ni = 0; ni < 2; ni++) {
      int pos = (nbase + ni) * 16 + row;
#pragma unroll
      for (int r = 0; r < 4; r++) {
        int d = mi * 16 + kg * 4 + r;
        f2out[d * 257 + pos] = acc2[mi][ni][r];
      }
    }
  __syncthreads();

  // ---- residual epilogue (coalesced) ----
  float* xb = x + (size_t)b * 8192;
#pragma unroll
  for (int j = 0; j < 16; j++) {
    int idx = tid + j * 512;            // 0..8191 = p1*512 + d*16 + p2
    int p1 = idx >> 9, dm = idx & 511;
    int d = dm >> 4, p2 = dm & 15;
    xb[idx] += f2out[d * 257 + p1 * 16 + p2] + f2b[d];
  }
}

extern "C" void kernel_launch(void* const* d_in, const int* in_sizes, int n_in,
                              void* d_out, int out_size, void* d_ws, size_t ws_size,
                              hipStream_t stream) {
  const float* x_in   = (const float*)d_in[0];
  const float* ln1_g  = (const float*)d_in[1];
  const float* ln1_b  = (const float*)d_in[2];
  const float* ln2_g  = (const float*)d_in[3];
  const float* ln2_b  = (const float*)d_in[4];
  const float* qkv_dw = (const float*)d_in[5];
  const float* qkv_bng = (const float*)d_in[6];
  const float* qkv_bnb = (const float*)d_in[7];
  const float* qkv_bnm = (const float*)d_in[8];
  const float* qkv_bnv = (const float*)d_in[9];
  const float* qkv_pw = (const float*)d_in[10];
  const float* position = (const float*)d_in[11];
  const float* c1d_w  = (const float*)d_in[12];
  const float* c1d_b  = (const float*)d_in[13];
  const float* lin_w  = (const float*)d_in[14];
  const float* lin_b  = (const float*)d_in[15];
  const float* f1_w   = (const float*)d_in[16];
  const float* f1_b   = (const float*)d_in[17];
  const float* fdw_w  = (const float*)d_in[18];
  const float* fdw_b  = (const float*)d_in[19];
  const float* f_bng  = (const float*)d_in[20];
  const float* f_bnb  = (const float*)d_in[21];
  const float* f_bnm  = (const float*)d_in[22];
  const float* f_bnv  = (const float*)d_in[23];
  const float* fpw_w  = (const float*)d_in[24];
  const float* fpw_b  = (const float*)d_in[25];
  const float* f2_w   = (const float*)d_in[26];
  const float* f2_b   = (const float*)d_in[27];

  float* xbuf = (float*)d_out;                       // running x lives in d_out
  float* q  = (float*)d_ws;                          // (B,32,64)
  float* k  = q + (size_t)B_ * 2048;
  float* v  = k + (size_t)B_ * 2048;
  float* xc = v + (size_t)B_ * 2048;                 // (B,16,256)
  float* wT = xc + (size_t)B_ * 4096;                // (2,256,512)
  __hip_bfloat16* y1 = (__hip_bfloat16*)(wT + 2 * 131072);  // (B,128,256) bf16

  hipMemcpyAsync(xbuf, x_in, (size_t)B_ * 8192 * sizeof(float),
                 hipMemcpyDeviceToDevice, stream);
  k_transpose<<<1024, 256, 0, stream>>>(lin_w, wT);
  for (int l = 0; l < 2; l++) {
    k_qkv<<<B_, 256, 0, stream>>>(xbuf, ln1_g + l * 512, ln1_b + l * 512,
        qkv_dw + l * 864, qkv_bng + l * 96, qkv_bnb + l * 96,
        qkv_bnm + l * 96, qkv_bnv + l * 96, qkv_pw + l * 3072, q, k, v);
    k_attn<<<B_, 256, 0, stream>>>(q, k, v, position + l * 1024,
        c1d_w + l * 128, c1d_b + l * 16, xc);
    k_lin<<<B_, 256, 0, stream>>>(xc, wT + l * 131072, lin_b + l * 512, xbuf);
    k_f1<<<B_, 256, 0, stream>>>(xbuf, ln2_g + l * 512, ln2_b + l * 512,
        f1_w + l * 4096, f1_b + l * 128, y1);
    k_ffn<<<B_, 512, 0, stream>>>(y1, fdw_w + l * 1152, fdw_b + l * 128,
        f_bng + l * 128, f_bnb + l * 128, f_bnm + l * 128, f_bnv + l * 128,
        fpw_w + l * 16384, fpw_b + l * 128, f2_w + l * 4096, f2_b + l * 32, xbuf);
  }
}

// Round 4
// 975.375 us; speedup vs baseline: 4.8142x; 1.9263x over previous
//
#include <hip/hip_runtime.h>
#include <hip/hip_bf16.h>

#define B_ 2048
#define EPSF 1e-5f

typedef __attribute__((ext_vector_type(8))) short short8v;
typedef __attribute__((ext_vector_type(4))) short short4v;
typedef __attribute__((ext_vector_type(4))) float f32x4;

// float -> bf16 bits, round-to-nearest-even
__device__ __forceinline__ short f2bf_s(float f) {
  union { float f; unsigned u; } v; v.f = f;
  unsigned r = v.u + 0x7fffu + ((v.u >> 16) & 1u);
  return (short)(r >> 16);
}
__device__ __forceinline__ float bf2f(short s) {
  return __uint_as_float(((unsigned)(unsigned short)s) << 16);
}

// ---------------- lin_w transpose: (2,512,256) -> (2,256,512) ----------------
__global__ __launch_bounds__(256) void k_transpose(const float* __restrict__ w,
                                                   float* __restrict__ wT) {
  int idx = blockIdx.x * 256 + threadIdx.x;          // 2*512*256 = 262144
  if (idx >= 2 * 512 * 256) return;
  int l = idx >> 17;
  int r = idx & 131071;
  int m = r >> 8;          // 0..511
  int d = r & 255;         // 0..255
  wT[l * 131072 + d * 512 + m] = w[idx];
}

// ---------------- weight prep: bf16 padded LDS images ------------------------
// f1wb: [l][128][40]   (K=32 padded to 40)        -> 2*5120 shorts
// img:  [l][ pw 128x136 | f2 32x136 ]             -> 2*21760 shorts
__global__ __launch_bounds__(256) void k_prep(
    const float* __restrict__ f1_w, const float* __restrict__ fpw_w,
    const float* __restrict__ f2_w, short* __restrict__ f1wb,
    short* __restrict__ img) {
  int i = blockIdx.x * 256 + threadIdx.x;
  if (i < 10240) {
    int l = i / 5120, r = i % 5120, o = r / 40, kk = r % 40;
    f1wb[i] = (kk < 32) ? f2bf_s(f1_w[l * 4096 + o * 32 + kk]) : (short)0;
  }
  if (i < 43520) {
    int l = i / 21760, r = i % 21760;
    short val;
    if (r < 17408) {
      int o = r / 136, kk = r % 136;
      val = (kk < 128) ? f2bf_s(fpw_w[l * 16384 + o * 128 + kk]) : (short)0;
    } else {
      int r2 = r - 17408;
      int d = r2 / 136, kk = r2 % 136;
      val = (kk < 128) ? f2bf_s(f2_w[l * 4096 + d * 128 + kk]) : (short)0;
    }
    img[l * 21760 + r] = val;
  }
}

// ---------------- shared helper: LN over 512 + to_patches into LDS (fp32) ----
__device__ __forceinline__ void ln_to_patches(const float* __restrict__ xb,
                                              const float* __restrict__ g,
                                              const float* __restrict__ beta,
                                              float (*p)[257], int tid) {
  int lane = tid & 63, wave = tid >> 6;
  for (int r = wave; r < 16; r += 4) {
    float vals[8];
    float s = 0.f, ss = 0.f;
#pragma unroll
    for (int j = 0; j < 8; j++) {
      float t = xb[r * 512 + lane + j * 64];
      vals[j] = t; s += t; ss += t * t;
    }
#pragma unroll
    for (int o = 32; o; o >>= 1) { s += __shfl_xor(s, o); ss += __shfl_xor(ss, o); }
    float m = s * (1.f / 512.f);
    float inv = rsqrtf(ss * (1.f / 512.f) - m * m + EPSF);
#pragma unroll
    for (int j = 0; j < 8; j++) {
      int col = lane + j * 64;
      p[col >> 4][r * 16 + (col & 15)] = (vals[j] - m) * inv * g[col] + beta[col];
    }
  }
}

// ---------------- K1: LN1 + patches + qkv (dw3x3 s2 + BN + pw 32x32) --------
__global__ __launch_bounds__(256) void k_qkv(
    const float* __restrict__ x, const float* __restrict__ g,
    const float* __restrict__ beta, const float* __restrict__ dw,
    const float* __restrict__ bng, const float* __restrict__ bnb,
    const float* __restrict__ bnm, const float* __restrict__ bnv,
    const float* __restrict__ pw, float* __restrict__ qout,
    float* __restrict__ kout, float* __restrict__ vout) {
  __shared__ float p[32][257];
  __shared__ float dwo[32][64];
  int b = blockIdx.x, tid = threadIdx.x;
  ln_to_patches(x + (size_t)b * 8192, g, beta, p, tid);
  __syncthreads();
  for (int i = 0; i < 3; i++) {
    const float* dwi = dw + i * 288;   // 32*9
    const float* pwi = pw + i * 1024;  // 32*32
#pragma unroll
    for (int j = 0; j < 8; j++) {
      int idx = tid + j * 256;
      int c = idx >> 6, pos = idx & 63;
      int oy = pos >> 3, ox = pos & 7;
      float acc = 0.f;
#pragma unroll
      for (int ky = 0; ky < 3; ky++) {
        int iy = 2 * oy + ky - 1;
        if (iy < 0 || iy > 15) continue;
#pragma unroll
        for (int kx = 0; kx < 3; kx++) {
          int ix = 2 * ox + kx - 1;
          if (ix < 0 || ix > 15) continue;
          acc += dwi[c * 9 + ky * 3 + kx] * p[c][iy * 16 + ix];
        }
      }
      float scale = bng[i * 32 + c] * rsqrtf(bnv[i * 32 + c] + EPSF);
      dwo[c][pos] = (acc - bnm[i * 32 + c]) * scale + bnb[i * 32 + c];
    }
    __syncthreads();
    float* out = (i == 0) ? qout : (i == 1) ? kout : vout;
#pragma unroll
    for (int j = 0; j < 8; j++) {
      int idx = tid + j * 256;
      int o = idx >> 6, pos = idx & 63;
      float acc = 0.f;
#pragma unroll
      for (int c = 0; c < 32; c++) acc += pwi[o * 32 + c] * dwo[c][pos];
      out[(size_t)b * 2048 + idx] = acc;
    }
    __syncthreads();
  }
}

// ---------------- K2: attention + reorder + c1d ------------------------------
__global__ __launch_bounds__(256) void k_attn(
    const float* __restrict__ q, const float* __restrict__ k,
    const float* __restrict__ v, const float* __restrict__ pos,
    const float* __restrict__ c1w, const float* __restrict__ c1b,
    float* __restrict__ xc) {
  __shared__ float qs[32][65], ks[32][65], vs[32][65];
  __shared__ float sc[32][33];
  __shared__ float os[32][65];
  int b = blockIdx.x, tid = threadIdx.x;
  size_t base = (size_t)b * 2048;
#pragma unroll
  for (int j = 0; j < 8; j++) {
    int idx = tid + j * 256;
    int d = idx >> 6, e = idx & 63;
    qs[d][e] = q[base + idx];
    ks[d][e] = k[base + idx];
    vs[d][e] = v[base + idx];
  }
  __syncthreads();
#pragma unroll
  for (int j = 0; j < 4; j++) {
    int idx = tid + j * 256;
    int d = idx >> 5, f = idx & 31;
    float acc = 0.f;
#pragma unroll
    for (int e = 0; e < 64; e++) acc += qs[d][e] * ks[f][e];
    sc[d][f] = acc * 0.125f + pos[d * 32 + f];
  }
  __syncthreads();
  if (tid < 32) {
    float mx = -1e30f;
#pragma unroll
    for (int f = 0; f < 32; f++) mx = fmaxf(mx, sc[tid][f]);
    float s = 0.f;
#pragma unroll
    for (int f = 0; f < 32; f++) { float e = __expf(sc[tid][f] - mx); sc[tid][f] = e; s += e; }
    float inv = 1.f / s;
#pragma unroll
    for (int f = 0; f < 32; f++) sc[tid][f] *= inv;
  }
  __syncthreads();
#pragma unroll
  for (int j = 0; j < 8; j++) {
    int idx = tid + j * 256;
    int d = idx >> 6, e = idx & 63;
    float acc = 0.f;
#pragma unroll
    for (int f = 0; f < 32; f++) acc += sc[d][f] * vs[f][e];
    os[d][e] = acc;
  }
  __syncthreads();
  // xc[u][dd*8+p2] = sum_c c1w[u][c] * os[dd][c*8+p2] + c1b[u]
#pragma unroll
  for (int j = 0; j < 16; j++) {
    int idx = tid + j * 256;          // 0..4095
    int u = idx >> 8, jj = idx & 255;
    int dd = jj >> 3, p2 = jj & 7;
    float acc = c1b[u];
#pragma unroll
    for (int c = 0; c < 8; c++) acc += c1w[u * 8 + c] * os[dd][c * 8 + p2];
    xc[(size_t)b * 4096 + idx] = acc;
  }
}

// ---------------- K3: lin (16x512 <- 16x256 @ 256x512) + residual ------------
__global__ __launch_bounds__(256) void k_lin(
    const float* __restrict__ xc, const float* __restrict__ wT,
    const float* __restrict__ bias, float* __restrict__ x) {
  __shared__ float xcl[16][256];
  int b = blockIdx.x, tid = threadIdx.x;
#pragma unroll
  for (int j = 0; j < 16; j++) {
    int idx = tid + j * 256;
    xcl[idx >> 8][idx & 255] = xc[(size_t)b * 4096 + idx];
  }
  __syncthreads();
  float acc0[16], acc1[16];
#pragma unroll
  for (int u = 0; u < 16; u++) { acc0[u] = 0.f; acc1[u] = 0.f; }
  int m0 = tid, m1 = tid + 256;
  for (int d = 0; d < 256; d++) {
    float w0 = wT[d * 512 + m0];
    float w1 = wT[d * 512 + m1];
#pragma unroll
    for (int u = 0; u < 16; u++) {
      float xv = xcl[u][d];
      acc0[u] += xv * w0;
      acc1[u] += xv * w1;
    }
  }
  float b0 = bias[m0], b1 = bias[m1];
  float* xb = x + (size_t)b * 8192;
#pragma unroll
  for (int u = 0; u < 16; u++) {
    xb[u * 512 + m0] += acc0[u] + b0;
    xb[u * 512 + m1] += acc1[u] + b1;
  }
}

// ---------------- K5: fused LN2+f1(MFMA)+dw3x3+BN+fpw(MFMA)+f2(MFMA)+resid ---
// LDS overlay (137216 B):
//   [0, 69632)        sT [256 pos][136 c] bf16   (phase >=2); during phase 1:
//       [0, 20480)    p_lds [256 pos][40] bf16   (LN2 patches, f1 B)
//       [20480,30720) f1w_lds [128 o][40] bf16   (f1 A)
//   [69632, 137216)   sY [128 c][264 pos] bf16   (y1); later:
//       +0      pw_lds  [128][136] bf16 (34816B) -> later f2out [32][257] f32
//       +34816  f2w_lds [32][136]  bf16 (8704B)
#define OFF_P   0
#define OFF_F1W 20480
#define OFF_T   0
#define OFF_Y   69632
__global__ __launch_bounds__(512) void k_ffn2(
    const float* __restrict__ x, const float* __restrict__ g,
    const float* __restrict__ beta, const short* __restrict__ f1wb,
    const float* __restrict__ f1b, const float* __restrict__ dww,
    const float* __restrict__ dwb, const float* __restrict__ bng,
    const float* __restrict__ bnb, const float* __restrict__ bnm,
    const float* __restrict__ bnv, const short* __restrict__ img,
    const float* __restrict__ pwb, const float* __restrict__ f2b,
    float* __restrict__ xg) {
  __shared__ __align__(16) char smem[137216];
  short* p_lds = (short*)(smem + OFF_P);
  short* f1w_lds = (short*)(smem + OFF_F1W);
  short* sT = (short*)(smem + OFF_T);
  short* sY = (short*)(smem + OFF_Y);
  short* pw_lds = (short*)(smem + OFF_Y);
  short* f2w_lds = (short*)(smem + OFF_Y + 34816);
  float* f2out = (float*)(smem + OFF_Y);

  int b = blockIdx.x, tid = threadIdx.x;
  int lane = tid & 63, wid = tid >> 6;
  int row = lane & 15, kg = lane >> 4;
  const float* xb = x + (size_t)b * 8192;

  // ---- prefetch fpw/f2 weight image into regs (consumed after conv) ----
  const uint4* imgu = (const uint4*)img;  // already layer-offset
  uint4 pf0 = imgu[tid], pf1 = imgu[tid + 512], pf2 = imgu[tid + 1024];
  uint4 pf3 = imgu[tid + 1536], pf4 = imgu[tid + 2048];
  uint4 pf5 = {};
  if (tid < 160) pf5 = imgu[tid + 2560];

  // ---- stage f1w ----
  {
    const uint4* src = (const uint4*)f1wb;   // layer-offset, 640 chunks
    uint4* dst = (uint4*)f1w_lds;
    dst[tid >= 512 ? 0 : tid] = src[tid >= 512 ? 0 : tid];  // tid<512 always
    if (tid < 128) dst[tid + 512] = src[tid + 512];
  }

  // ---- LN2 + patches -> p_lds [pos][40] bf16 ----
  for (int r = wid; r < 16; r += 8) {
    float vals[8];
    float s = 0.f, ss = 0.f;
#pragma unroll
    for (int j = 0; j < 8; j++) {
      float t = xb[r * 512 + lane + j * 64];
      vals[j] = t; s += t; ss += t * t;
    }
#pragma unroll
    for (int o = 32; o; o >>= 1) { s += __shfl_xor(s, o); ss += __shfl_xor(ss, o); }
    float m = s * (1.f / 512.f);
    float inv = rsqrtf(ss * (1.f / 512.f) - m * m + EPSF);
#pragma unroll
    for (int j = 0; j < 8; j++) {
      int col = lane + j * 64;
      float nv = (vals[j] - m) * inv * g[col] + beta[col];
      p_lds[(r * 16 + (col & 15)) * 40 + (col >> 4)] = f2bf_s(nv);
    }
  }
  __syncthreads();

  // ---- f1 MFMA: y1[o=128][pos=256], K=32; wave tile 64x64 ----
  {
    int o0 = (wid & 1) * 64, pos0 = (wid >> 1) * 64;
    f32x4 acc[4][4] = {};
    short8v a[4], bb[4];
#pragma unroll
    for (int mi = 0; mi < 4; mi++)
      a[mi] = *(const short8v*)&f1w_lds[(o0 + mi * 16 + row) * 40 + kg * 8];
#pragma unroll
    for (int ni = 0; ni < 4; ni++)
      bb[ni] = *(const short8v*)&p_lds[(pos0 + ni * 16 + row) * 40 + kg * 8];
#pragma unroll
    for (int mi = 0; mi < 4; mi++)
#pragma unroll
      for (int ni = 0; ni < 4; ni++)
        acc[mi][ni] = __builtin_amdgcn_mfma_f32_16x16x32_bf16(a[mi], bb[ni], acc[mi][ni], 0, 0, 0);
    // bias + ReLU -> sY[c][pos] (stride 264)
#pragma unroll
    for (int mi = 0; mi < 4; mi++) {
      int obase = o0 + mi * 16 + kg * 4;
      float b0 = f1b[obase], b1 = f1b[obase + 1], b2 = f1b[obase + 2], b3 = f1b[obase + 3];
#pragma unroll
      for (int ni = 0; ni < 4; ni++) {
        int pos = pos0 + ni * 16 + row;
        sY[(obase + 0) * 264 + pos] = f2bf_s(fmaxf(acc[mi][ni][0] + b0, 0.f));
        sY[(obase + 1) * 264 + pos] = f2bf_s(fmaxf(acc[mi][ni][1] + b1, 0.f));
        sY[(obase + 2) * 264 + pos] = f2bf_s(fmaxf(acc[mi][ni][2] + b2, 0.f));
        sY[(obase + 3) * 264 + pos] = f2bf_s(fmaxf(acc[mi][ni][3] + b3, 0.f));
      }
    }
  }
  __syncthreads();

  // ---- depthwise 3x3 s1 + bias + BN -> sT[pos][136] bf16 ----
  {
    int c = tid & 127, hb = tid >> 7;       // 4 rows per thread
    float wgt[3][3];
#pragma unroll
    for (int rr = 0; rr < 3; rr++)
#pragma unroll
      for (int kx = 0; kx < 3; kx++) wgt[rr][kx] = dww[c * 9 + rr * 3 + kx];
    float bias = dwb[c];
    float scale = bng[c] * rsqrtf(bnv[c] + EPSF);
    float shift = bnb[c] - bnm[c] * scale;
#pragma unroll
    for (int j = 0; j < 4; j++) {
      int h = hb * 4 + j;
      float fr0[18], fr1[18], fr2[18];
#pragma unroll
      for (int i = 0; i < 18; i++) { fr0[i] = 0.f; fr1[i] = 0.f; fr2[i] = 0.f; }
      if (h > 0) {
        short8v s0 = *(const short8v*)&sY[c * 264 + (h - 1) * 16];
        short8v s1 = *(const short8v*)&sY[c * 264 + (h - 1) * 16 + 8];
#pragma unroll
        for (int i = 0; i < 8; i++) { fr0[1 + i] = bf2f(s0[i]); fr0[9 + i] = bf2f(s1[i]); }
      }
      {
        short8v s0 = *(const short8v*)&sY[c * 264 + h * 16];
        short8v s1 = *(const short8v*)&sY[c * 264 + h * 16 + 8];
#pragma unroll
        for (int i = 0; i < 8; i++) { fr1[1 + i] = bf2f(s0[i]); fr1[9 + i] = bf2f(s1[i]); }
      }
      if (h < 15) {
        short8v s0 = *(const short8v*)&sY[c * 264 + (h + 1) * 16];
        short8v s1 = *(const short8v*)&sY[c * 264 + (h + 1) * 16 + 8];
#pragma unroll
        for (int i = 0; i < 8; i++) { fr2[1 + i] = bf2f(s0[i]); fr2[9 + i] = bf2f(s1[i]); }
      }
#pragma unroll
      for (int w = 0; w < 16; w++) {
        float acc = bias;
#pragma unroll
        for (int kx = 0; kx < 3; kx++) {
          acc += wgt[0][kx] * fr0[w + kx];
          acc += wgt[1][kx] * fr1[w + kx];
          acc += wgt[2][kx] * fr2[w + kx];
        }
        sT[(h * 16 + w) * 136 + c] = f2bf_s(acc * scale + shift);
      }
    }
  }
  __syncthreads();

  // ---- drop prefetched weights into sY region ----
  {
    uint4* wdst = (uint4*)pw_lds;
    wdst[tid] = pf0; wdst[tid + 512] = pf1; wdst[tid + 1024] = pf2;
    wdst[tid + 1536] = pf3; wdst[tid + 2048] = pf4;
    if (tid < 160) wdst[tid + 2560] = pf5;
  }
  __syncthreads();

  // ---- fpw MFMA: r[o=128][pos=256], K=128; wave tile 64x64 ----
  int o0 = (wid & 1) * 64, pos0 = (wid >> 1) * 64;
  f32x4 acc[4][4] = {};
#pragma unroll
  for (int kk = 0; kk < 4; kk++) {
    int k0 = kk * 32 + kg * 8;
    short8v a[4], bb[4];
#pragma unroll
    for (int mi = 0; mi < 4; mi++)
      a[mi] = *(const short8v*)&pw_lds[(o0 + mi * 16 + row) * 136 + k0];
#pragma unroll
    for (int ni = 0; ni < 4; ni++)
      bb[ni] = *(const short8v*)&sT[(pos0 + ni * 16 + row) * 136 + k0];
#pragma unroll
    for (int mi = 0; mi < 4; mi++)
#pragma unroll
      for (int ni = 0; ni < 4; ni++)
        acc[mi][ni] = __builtin_amdgcn_mfma_f32_16x16x32_bf16(a[mi], bb[ni], acc[mi][ni], 0, 0, 0);
  }
  __syncthreads();  // all fpw reads of sT/pw_lds done

  // ---- bias + ReLU -> sT[pos][o] (overwrite) ----
#pragma unroll
  for (int mi = 0; mi < 4; mi++) {
    int obase = o0 + mi * 16 + kg * 4;
    float pb0 = pwb[obase], pb1 = pwb[obase + 1], pb2 = pwb[obase + 2], pb3 = pwb[obase + 3];
#pragma unroll
    for (int ni = 0; ni < 4; ni++) {
      int pos = pos0 + ni * 16 + row;
      short4v pk;
      pk.x = f2bf_s(fmaxf(acc[mi][ni][0] + pb0, 0.f));
      pk.y = f2bf_s(fmaxf(acc[mi][ni][1] + pb1, 0.f));
      pk.z = f2bf_s(fmaxf(acc[mi][ni][2] + pb2, 0.f));
      pk.w = f2bf_s(fmaxf(acc[mi][ni][3] + pb3, 0.f));
      *(short4v*)&sT[pos * 136 + obase] = pk;
    }
  }
  __syncthreads();

  // ---- f2 MFMA: out[d=32][pos=256], K=128 ----
  {
    f32x4 acc2[2][2] = {};
    int nbase = wid * 2;
#pragma unroll
    for (int kk = 0; kk < 4; kk++) {
      int k0 = kk * 32 + kg * 8;
      short8v a2[2], b2[2];
#pragma unroll
      for (int mi = 0; mi < 2; mi++)
        a2[mi] = *(const short8v*)&f2w_lds[(mi * 16 + row) * 136 + k0];
#pragma unroll
      for (int ni = 0; ni < 2; ni++)
        b2[ni] = *(const short8v*)&sT[((nbase + ni) * 16 + row) * 136 + k0];
#pragma unroll
      for (int mi = 0; mi < 2; mi++)
#pragma unroll
        for (int ni = 0; ni < 2; ni++)
          acc2[mi][ni] = __builtin_amdgcn_mfma_f32_16x16x32_bf16(a2[mi], b2[ni], acc2[mi][ni], 0, 0, 0);
    }
#pragma unroll
    for (int mi = 0; mi < 2; mi++)
#pragma unroll
      for (int ni = 0; ni < 2; ni++) {
        int pos = (nbase + ni) * 16 + row;
        int dbase = mi * 16 + kg * 4;
        f2out[(dbase + 0) * 257 + pos] = acc2[mi][ni][0];
        f2out[(dbase + 1) * 257 + pos] = acc2[mi][ni][1];
        f2out[(dbase + 2) * 257 + pos] = acc2[mi][ni][2];
        f2out[(dbase + 3) * 257 + pos] = acc2[mi][ni][3];
      }
  }
  __syncthreads();

  // ---- residual epilogue (coalesced) ----
  float* xo = xg + (size_t)b * 8192;
#pragma unroll
  for (int j = 0; j < 16; j++) {
    int idx = tid + j * 512;            // p1*512 + d*16 + p2
    int dm = idx & 511;
    int d = dm >> 4, p2 = dm & 15;
    int p1 = idx >> 9;
    xo[idx] += f2out[d * 257 + p1 * 16 + p2] + f2b[d];
  }
}

extern "C" void kernel_launch(void* const* d_in, const int* in_sizes, int n_in,
                              void* d_out, int out_size, void* d_ws, size_t ws_size,
                              hipStream_t stream) {
  const float* x_in   = (const float*)d_in[0];
  const float* ln1_g  = (const float*)d_in[1];
  const float* ln1_b  = (const float*)d_in[2];
  const float* ln2_g  = (const float*)d_in[3];
  const float* ln2_b  = (const float*)d_in[4];
  const float* qkv_dw = (const float*)d_in[5];
  const float* qkv_bng = (const float*)d_in[6];
  const float* qkv_bnb = (const float*)d_in[7];
  const float* qkv_bnm = (const float*)d_in[8];
  const float* qkv_bnv = (const float*)d_in[9];
  const float* qkv_pw = (const float*)d_in[10];
  const float* position = (const float*)d_in[11];
  const float* c1d_w  = (const float*)d_in[12];
  const float* c1d_b  = (const float*)d_in[13];
  const float* lin_w  = (const float*)d_in[14];
  const float* lin_b  = (const float*)d_in[15];
  const float* f1_w   = (const float*)d_in[16];
  const float* f1_b   = (const float*)d_in[17];
  const float* fdw_w  = (const float*)d_in[18];
  const float* fdw_b  = (const float*)d_in[19];
  const float* f_bng  = (const float*)d_in[20];
  const float* f_bnb  = (const float*)d_in[21];
  const float* f_bnm  = (const float*)d_in[22];
  const float* f_bnv  = (const float*)d_in[23];
  const float* fpw_w  = (const float*)d_in[24];
  const float* fpw_b  = (const float*)d_in[25];
  const float* f2_w   = (const float*)d_in[26];
  const float* f2_b   = (const float*)d_in[27];

  float* xbuf = (float*)d_out;                       // running x lives in d_out
  float* q  = (float*)d_ws;                          // (B,32,64)
  float* k  = q + (size_t)B_ * 2048;
  float* v  = k + (size_t)B_ * 2048;
  float* xc = v + (size_t)B_ * 2048;                 // (B,16,256)
  float* wT = xc + (size_t)B_ * 4096;                // (2,256,512)
  short* f1wb = (short*)(wT + 2 * 131072);           // 2*5120 bf16
  short* img  = f1wb + 2 * 5120;                     // 2*21760 bf16

  hipMemcpyAsync(xbuf, x_in, (size_t)B_ * 8192 * sizeof(float),
                 hipMemcpyDeviceToDevice, stream);
  k_transpose<<<1024, 256, 0, stream>>>(lin_w, wT);
  k_prep<<<170, 256, 0, stream>>>(f1_w, fpw_w, f2_w, f1wb, img);
  for (int l = 0; l < 2; l++) {
    k_qkv<<<B_, 256, 0, stream>>>(xbuf, ln1_g + l * 512, ln1_b + l * 512,
        qkv_dw + l * 864, qkv_bng + l * 96, qkv_bnb + l * 96,
        qkv_bnm + l * 96, qkv_bnv + l * 96, qkv_pw + l * 3072, q, k, v);
    k_attn<<<B_, 256, 0, stream>>>(q, k, v, position + l * 1024,
        c1d_w + l * 128, c1d_b + l * 16, xc);
    k_lin<<<B_, 256, 0, stream>>>(xc, wT + l * 131072, lin_b + l * 512, xbuf);
    k_ffn2<<<B_, 512, 0, stream>>>(xbuf, ln2_g + l * 512, ln2_b + l * 512,
        f1wb + l * 5120, f1_b + l * 128, fdw_w + l * 1152, fdw_b + l * 128,
        f_bng + l * 128, f_bnb + l * 128, f_bnm + l * 128, f_bnv + l * 128,
        img + l * 21760, fpw_b + l * 128, f2_b + l * 32, xbuf);
  }
}

// Round 5
// 427.096 us; speedup vs baseline: 10.9944x; 2.2837x over previous
//
#include <hip/hip_runtime.h>
#include <hip/hip_bf16.h>

#define B_ 2048
#define EPSF 1e-5f

typedef __attribute__((ext_vector_type(8))) short short8v;
typedef __attribute__((ext_vector_type(4))) short short4v;
typedef __attribute__((ext_vector_type(4))) float f32x4;

// float -> bf16 bits, round-to-nearest-even
__device__ __forceinline__ short f2bf_s(float f) {
  union { float f; unsigned u; } v; v.f = f;
  unsigned r = v.u + 0x7fffu + ((v.u >> 16) & 1u);
  return (short)(r >> 16);
}
__device__ __forceinline__ float bf2f(short s) {
  return __uint_as_float(((unsigned)(unsigned short)s) << 16);
}

// ---------------- weight prep: bf16 images ----------------------------------
// f1wb: [l][128][40]       (K=32 pad 40)       10240 shorts
// img:  [l][pw 128x136 | f2 32x136]            43520 shorts
// qkvA: [l][3][32][40]     (K=32 pad 40)        7680 shorts
// linb: [l][512][256]                         262144 shorts
__global__ __launch_bounds__(256) void k_prep(
    const float* __restrict__ f1_w, const float* __restrict__ fpw_w,
    const float* __restrict__ f2_w, const float* __restrict__ qkv_pw,
    const float* __restrict__ lin_w, short* __restrict__ f1wb,
    short* __restrict__ img, short* __restrict__ qkvA,
    short* __restrict__ linb) {
  int i = blockIdx.x * 256 + threadIdx.x;
  if (i < 10240) {
    int l = i / 5120, r = i % 5120, o = r / 40, kk = r % 40;
    f1wb[i] = (kk < 32) ? f2bf_s(f1_w[l * 4096 + o * 32 + kk]) : (short)0;
  }
  if (i < 43520) {
    int l = i / 21760, r = i % 21760;
    short val;
    if (r < 17408) {
      int o = r / 136, kk = r % 136;
      val = (kk < 128) ? f2bf_s(fpw_w[l * 16384 + o * 128 + kk]) : (short)0;
    } else {
      int r2 = r - 17408;
      int d = r2 / 136, kk = r2 % 136;
      val = (kk < 128) ? f2bf_s(f2_w[l * 4096 + d * 128 + kk]) : (short)0;
    }
    img[l * 21760 + r] = val;
  }
  if (i < 7680) {
    int l = i / 3840, r = i % 3840;
    int io = r / 40, c = r % 40;    // io = iw*32 + o
    qkvA[i] = (c < 32) ? f2bf_s(qkv_pw[l * 3072 + io * 32 + c]) : (short)0;
  }
  if (i < 262144) linb[i] = f2bf_s(lin_w[i]);
}

// ---------------- shared helper: LN over 512 + to_patches into LDS (fp32) ----
__device__ __forceinline__ void ln_to_patches(const float* __restrict__ xb,
                                              const float* __restrict__ g,
                                              const float* __restrict__ beta,
                                              float (*p)[257], int tid) {
  int lane = tid & 63, wave = tid >> 6;
  for (int r = wave; r < 16; r += 4) {
    float vals[8];
    float s = 0.f, ss = 0.f;
#pragma unroll
    for (int j = 0; j < 8; j++) {
      float t = xb[r * 512 + lane + j * 64];
      vals[j] = t; s += t; ss += t * t;
    }
#pragma unroll
    for (int o = 32; o; o >>= 1) { s += __shfl_xor(s, o); ss += __shfl_xor(ss, o); }
    float m = s * (1.f / 512.f);
    float inv = rsqrtf(ss * (1.f / 512.f) - m * m + EPSF);
#pragma unroll
    for (int j = 0; j < 8; j++) {
      int col = lane + j * 64;
      p[col >> 4][r * 16 + (col & 15)] = (vals[j] - m) * inv * g[col] + beta[col];
    }
  }
}

// ---------------- K_ATT: fused LN1+qkv+attention+c1d+lin+residual ------------
// LDS overlay (62592 B):
//   [0, 32896)  p fp32 [32][257]; after conv reused:
//       +0      sc fp32 [32][33]     (4224)
//       +4224   pa bf16 [32][40]     (2560)
//       +6784   ore bf16 [8][264]    (4224)
//       +11008  xc1 bf16 [16][264]   (8448)
//   [32896, 48256)  t3 bf16 [3][64][40]
//   [48256, 52864)  qe bf16 [32][72]
//   [52864, 57472)  ke bf16 [32][72]
//   [57472, 62592)  vt bf16 [64][40]
__global__ __launch_bounds__(256) void k_att(
    const float* __restrict__ x, const float* __restrict__ g,
    const float* __restrict__ beta, const float* __restrict__ dw,
    const float* __restrict__ bng, const float* __restrict__ bnb,
    const float* __restrict__ bnm, const float* __restrict__ bnv,
    const short* __restrict__ qkvA, const float* __restrict__ posn,
    const float* __restrict__ c1w, const float* __restrict__ c1b,
    const short* __restrict__ linb, const float* __restrict__ lin_b,
    float* __restrict__ xg) {
  __shared__ __align__(16) char smem[62592];
  float (*p)[257] = (float(*)[257])smem;
  float* sc  = (float*)(smem + 0);
  short* pa  = (short*)(smem + 4224);
  short* ore = (short*)(smem + 6784);
  short* xc1 = (short*)(smem + 11008);
  short* t3s = (short*)(smem + 32896);
  short* qe  = (short*)(smem + 48256);
  short* ke  = (short*)(smem + 52864);
  short* vt  = (short*)(smem + 57472);

  int b = blockIdx.x, tid = threadIdx.x;
  int lane = tid & 63, wid = tid >> 6;
  int row = lane & 15, kg = lane >> 4;
  const float* xb = x + (size_t)b * 8192;

  // ---- Phase 1: LN1 + to_patches ----
  ln_to_patches(xb, g, beta, p, tid);
  __syncthreads();

  // ---- Phase 2: dw 3x3 s2 + BN (x3) -> t3[i][pos][c] (lane<->channel!) ----
  {
    int c = tid & 31, oy = tid >> 5;
    float r0[16], r1[16], r2[16];
    int iy0 = 2 * oy - 1;
#pragma unroll
    for (int i = 0; i < 16; i++) {
      r0[i] = (iy0 >= 0) ? p[c][iy0 * 16 + i] : 0.f;
      r1[i] = p[c][(2 * oy) * 16 + i];
      r2[i] = p[c][(2 * oy + 1) * 16 + i];
    }
    for (int iw = 0; iw < 3; iw++) {
      const float* w9 = dw + iw * 288 + c * 9;
      float w00 = w9[0], w01 = w9[1], w02 = w9[2];
      float w10 = w9[3], w11 = w9[4], w12 = w9[5];
      float w20 = w9[6], w21 = w9[7], w22 = w9[8];
      float scale = bng[iw * 32 + c] * rsqrtf(bnv[iw * 32 + c] + EPSF);
      float shift = bnb[iw * 32 + c] - bnm[iw * 32 + c] * scale;
#pragma unroll
      for (int ox = 0; ox < 8; ox++) {
        int ix = 2 * ox;
        float acc = w01 * r0[ix] + w11 * r1[ix] + w21 * r2[ix]
                  + w02 * r0[ix + 1] + w12 * r1[ix + 1] + w22 * r2[ix + 1];
        if (ix > 0) acc += w00 * r0[ix - 1] + w10 * r1[ix - 1] + w20 * r2[ix - 1];
        t3s[(iw * 64 + oy * 8 + ox) * 40 + c] = f2bf_s(acc * scale + shift);
      }
    }
  }
  __syncthreads();

  // ---- Phase 3: pw MFMA (32x64, K=32) x3 -> qe[d][e], ke[d][e], vt[e][f] ----
  {
    int mi = wid & 1, nbase = (wid >> 1) * 2;
    for (int iw = 0; iw < 3; iw++) {
      short8v a = *(const short8v*)&qkvA[(iw * 32 + mi * 16 + row) * 40 + kg * 8];
      short8v b0 = *(const short8v*)&t3s[(iw * 64 + (nbase + 0) * 16 + row) * 40 + kg * 8];
      short8v b1 = *(const short8v*)&t3s[(iw * 64 + (nbase + 1) * 16 + row) * 40 + kg * 8];
      f32x4 z = {};
      f32x4 acc0 = __builtin_amdgcn_mfma_f32_16x16x32_bf16(a, b0, z, 0, 0, 0);
      f32x4 acc1 = __builtin_amdgcn_mfma_f32_16x16x32_bf16(a, b1, z, 0, 0, 0);
      if (iw < 2) {
        short* tgt = (iw == 0) ? qe : ke;
#pragma unroll
        for (int r = 0; r < 4; r++) {
          int d = mi * 16 + kg * 4 + r;
          tgt[d * 72 + (nbase + 0) * 16 + row] = f2bf_s(acc0[r]);
          tgt[d * 72 + (nbase + 1) * 16 + row] = f2bf_s(acc1[r]);
        }
      } else {
        int e0 = (nbase + 0) * 16 + row, e1 = (nbase + 1) * 16 + row;
        int fb = mi * 16 + kg * 4;
        short4v v0, v1;
        v0.x = f2bf_s(acc0[0]); v0.y = f2bf_s(acc0[1]);
        v0.z = f2bf_s(acc0[2]); v0.w = f2bf_s(acc0[3]);
        v1.x = f2bf_s(acc1[0]); v1.y = f2bf_s(acc1[1]);
        v1.z = f2bf_s(acc1[2]); v1.w = f2bf_s(acc1[3]);
        *(short4v*)&vt[e0 * 40 + fb] = v0;
        *(short4v*)&vt[e1 * 40 + fb] = v1;
      }
    }
  }
  __syncthreads();

  // ---- Phase 4: QK^T (32x32, K=64) * 1/8 + position -> sc fp32 ----
  {
    int mi = wid & 1, ni = wid >> 1;
    f32x4 acc = {};
#pragma unroll
    for (int kk = 0; kk < 2; kk++) {
      short8v a = *(const short8v*)&qe[(mi * 16 + row) * 72 + kk * 32 + kg * 8];
      short8v bb = *(const short8v*)&ke[(ni * 16 + row) * 72 + kk * 32 + kg * 8];
      acc = __builtin_amdgcn_mfma_f32_16x16x32_bf16(a, bb, acc, 0, 0, 0);
    }
#pragma unroll
    for (int r = 0; r < 4; r++) {
      int d = mi * 16 + kg * 4 + r, f = ni * 16 + row;
      sc[d * 33 + f] = acc[r] * 0.125f + posn[d * 32 + f];
    }
  }
  __syncthreads();

  // ---- Phase 5: softmax rows (8 threads/row) -> pa bf16 ----
  {
    int srow = tid >> 3, sg = tid & 7;
    float v0 = sc[srow * 33 + sg * 4 + 0];
    float v1 = sc[srow * 33 + sg * 4 + 1];
    float v2 = sc[srow * 33 + sg * 4 + 2];
    float v3 = sc[srow * 33 + sg * 4 + 3];
    float mx = fmaxf(fmaxf(v0, v1), fmaxf(v2, v3));
    mx = fmaxf(mx, __shfl_xor(mx, 1));
    mx = fmaxf(mx, __shfl_xor(mx, 2));
    mx = fmaxf(mx, __shfl_xor(mx, 4));
    float e0 = __expf(v0 - mx), e1 = __expf(v1 - mx);
    float e2 = __expf(v2 - mx), e3 = __expf(v3 - mx);
    float s = e0 + e1 + e2 + e3;
    s += __shfl_xor(s, 1); s += __shfl_xor(s, 2); s += __shfl_xor(s, 4);
    float inv = 1.f / s;
    short4v pk;
    pk.x = f2bf_s(e0 * inv); pk.y = f2bf_s(e1 * inv);
    pk.z = f2bf_s(e2 * inv); pk.w = f2bf_s(e3 * inv);
    *(short4v*)&pa[srow * 40 + sg * 4] = pk;
  }
  __syncthreads();

  // ---- Phase 6: PV (32x64, K=32) -> ore[p1][d*8+p2] ----
  {
    int mi = wid & 1, nbase = (wid >> 1) * 2;
    short8v a = *(const short8v*)&pa[(mi * 16 + row) * 40 + kg * 8];
#pragma unroll
    for (int t = 0; t < 2; t++) {
      int e = (nbase + t) * 16 + row;
      short8v bb = *(const short8v*)&vt[e * 40 + kg * 8];
      f32x4 z = {};
      f32x4 acc = __builtin_amdgcn_mfma_f32_16x16x32_bf16(a, bb, z, 0, 0, 0);
#pragma unroll
      for (int r = 0; r < 4; r++) {
        int d = mi * 16 + kg * 4 + r;
        ore[(e >> 3) * 264 + d * 8 + (e & 7)] = f2bf_s(acc[r]);
      }
    }
  }
  __syncthreads();

  // ---- Phase 7: c1d (16x256, K=8 scalar) -> xc1 bf16 ----
  {
    int n = tid;
#pragma unroll
    for (int u = 0; u < 16; u++) {
      float acc = c1b[u];
#pragma unroll
      for (int c = 0; c < 8; c++)
        acc += c1w[u * 8 + c] * bf2f(ore[c * 264 + n]);
      xc1[u * 264 + n] = f2bf_s(acc);
    }
  }
  __syncthreads();

  // ---- Phase 8: lin MFMA (16x512, K=256) + bias + residual ----
  {
    short8v a8[8];
#pragma unroll
    for (int kk = 0; kk < 8; kk++)
      a8[kk] = *(const short8v*)&xc1[row * 264 + kk * 32 + kg * 8];
    float* xo = xg + (size_t)b * 8192;
    for (int t = 0; t < 8; t++) {
      int nt = wid * 8 + t;
      const short* bb_base = linb + (nt * 16 + row) * 256 + kg * 8;
      f32x4 acc = {};
#pragma unroll
      for (int kk = 0; kk < 8; kk++) {
        short8v bb = *(const short8v*)(bb_base + kk * 32);
        acc = __builtin_amdgcn_mfma_f32_16x16x32_bf16(a8[kk], bb, acc, 0, 0, 0);
      }
      int m = nt * 16 + row;
      float lb = lin_b[m];
#pragma unroll
      for (int r = 0; r < 4; r++) {
        int u = kg * 4 + r;
        xo[u * 512 + m] += acc[r] + lb;
      }
    }
  }
}

// ---------------- K5: fused LN2+f1(MFMA)+dw3x3+BN+fpw(MFMA)+f2(MFMA)+resid ---
#define OFF_P   0
#define OFF_F1W 20480
#define OFF_T   0
#define OFF_Y   69632
__global__ __launch_bounds__(512) void k_ffn2(
    const float* __restrict__ x, const float* __restrict__ g,
    const float* __restrict__ beta, const short* __restrict__ f1wb,
    const float* __restrict__ f1b, const float* __restrict__ dww,
    const float* __restrict__ dwb, const float* __restrict__ bng,
    const float* __restrict__ bnb, const float* __restrict__ bnm,
    const float* __restrict__ bnv, const short* __restrict__ img,
    const float* __restrict__ pwb, const float* __restrict__ f2b,
    float* __restrict__ xg) {
  __shared__ __align__(16) char smem[137216];
  short* p_lds = (short*)(smem + OFF_P);
  short* f1w_lds = (short*)(smem + OFF_F1W);
  short* sT = (short*)(smem + OFF_T);
  short* sY = (short*)(smem + OFF_Y);
  short* pw_lds = (short*)(smem + OFF_Y);
  short* f2w_lds = (short*)(smem + OFF_Y + 34816);
  float* f2out = (float*)(smem + OFF_Y);

  int b = blockIdx.x, tid = threadIdx.x;
  int lane = tid & 63, wid = tid >> 6;
  int row = lane & 15, kg = lane >> 4;
  const float* xb = x + (size_t)b * 8192;

  // ---- prefetch fpw/f2 weight image into regs (consumed after conv) ----
  const uint4* imgu = (const uint4*)img;
  uint4 pf0 = imgu[tid], pf1 = imgu[tid + 512], pf2 = imgu[tid + 1024];
  uint4 pf3 = imgu[tid + 1536], pf4 = imgu[tid + 2048];
  uint4 pf5 = {};
  if (tid < 160) pf5 = imgu[tid + 2560];

  // ---- stage f1w ----
  {
    const uint4* src = (const uint4*)f1wb;
    uint4* dst = (uint4*)f1w_lds;
    dst[tid >= 512 ? 0 : tid] = src[tid >= 512 ? 0 : tid];
    if (tid < 128) dst[tid + 512] = src[tid + 512];
  }

  // ---- LN2 + patches -> p_lds [pos][40] bf16 ----
  for (int r = wid; r < 16; r += 8) {
    float vals[8];
    float s = 0.f, ss = 0.f;
#pragma unroll
    for (int j = 0; j < 8; j++) {
      float t = xb[r * 512 + lane + j * 64];
      vals[j] = t; s += t; ss += t * t;
    }
#pragma unroll
    for (int o = 32; o; o >>= 1) { s += __shfl_xor(s, o); ss += __shfl_xor(ss, o); }
    float m = s * (1.f / 512.f);
    float inv = rsqrtf(ss * (1.f / 512.f) - m * m + EPSF);
#pragma unroll
    for (int j = 0; j < 8; j++) {
      int col = lane + j * 64;
      float nv = (vals[j] - m) * inv * g[col] + beta[col];
      p_lds[(r * 16 + (col & 15)) * 40 + (col >> 4)] = f2bf_s(nv);
    }
  }
  __syncthreads();

  // ---- f1 MFMA: y1[o=128][pos=256], K=32; wave tile 64x64 ----
  {
    int o0 = (wid & 1) * 64, pos0 = (wid >> 1) * 64;
    f32x4 acc[4][4] = {};
    short8v a[4], bb[4];
#pragma unroll
    for (int mi = 0; mi < 4; mi++)
      a[mi] = *(const short8v*)&f1w_lds[(o0 + mi * 16 + row) * 40 + kg * 8];
#pragma unroll
    for (int ni = 0; ni < 4; ni++)
      bb[ni] = *(const short8v*)&p_lds[(pos0 + ni * 16 + row) * 40 + kg * 8];
#pragma unroll
    for (int mi = 0; mi < 4; mi++)
#pragma unroll
      for (int ni = 0; ni < 4; ni++)
        acc[mi][ni] = __builtin_amdgcn_mfma_f32_16x16x32_bf16(a[mi], bb[ni], acc[mi][ni], 0, 0, 0);
#pragma unroll
    for (int mi = 0; mi < 4; mi++) {
      int obase = o0 + mi * 16 + kg * 4;
      float b0 = f1b[obase], b1 = f1b[obase + 1], b2 = f1b[obase + 2], b3 = f1b[obase + 3];
#pragma unroll
      for (int ni = 0; ni < 4; ni++) {
        int pos = pos0 + ni * 16 + row;
        sY[(obase + 0) * 264 + pos] = f2bf_s(fmaxf(acc[mi][ni][0] + b0, 0.f));
        sY[(obase + 1) * 264 + pos] = f2bf_s(fmaxf(acc[mi][ni][1] + b1, 0.f));
        sY[(obase + 2) * 264 + pos] = f2bf_s(fmaxf(acc[mi][ni][2] + b2, 0.f));
        sY[(obase + 3) * 264 + pos] = f2bf_s(fmaxf(acc[mi][ni][3] + b3, 0.f));
      }
    }
  }
  __syncthreads();

  // ---- depthwise 3x3 s1 + bias + BN -> sT[pos][136] bf16 ----
  {
    int c = tid & 127, hb = tid >> 7;
    float wgt[3][3];
#pragma unroll
    for (int rr = 0; rr < 3; rr++)
#pragma unroll
      for (int kx = 0; kx < 3; kx++) wgt[rr][kx] = dww[c * 9 + rr * 3 + kx];
    float bias = dwb[c];
    float scale = bng[c] * rsqrtf(bnv[c] + EPSF);
    float shift = bnb[c] - bnm[c] * scale;
#pragma unroll
    for (int j = 0; j < 4; j++) {
      int h = hb * 4 + j;
      float fr0[18], fr1[18], fr2[18];
#pragma unroll
      for (int i = 0; i < 18; i++) { fr0[i] = 0.f; fr1[i] = 0.f; fr2[i] = 0.f; }
      if (h > 0) {
        short8v s0 = *(const short8v*)&sY[c * 264 + (h - 1) * 16];
        short8v s1 = *(const short8v*)&sY[c * 264 + (h - 1) * 16 + 8];
#pragma unroll
        for (int i = 0; i < 8; i++) { fr0[1 + i] = bf2f(s0[i]); fr0[9 + i] = bf2f(s1[i]); }
      }
      {
        short8v s0 = *(const short8v*)&sY[c * 264 + h * 16];
        short8v s1 = *(const short8v*)&sY[c * 264 + h * 16 + 8];
#pragma unroll
        for (int i = 0; i < 8; i++) { fr1[1 + i] = bf2f(s0[i]); fr1[9 + i] = bf2f(s1[i]); }
      }
      if (h < 15) {
        short8v s0 = *(const short8v*)&sY[c * 264 + (h + 1) * 16];
        short8v s1 = *(const short8v*)&sY[c * 264 + (h + 1) * 16 + 8];
#pragma unroll
        for (int i = 0; i < 8; i++) { fr2[1 + i] = bf2f(s0[i]); fr2[9 + i] = bf2f(s1[i]); }
      }
#pragma unroll
      for (int w = 0; w < 16; w++) {
        float acc = bias;
#pragma unroll
        for (int kx = 0; kx < 3; kx++) {
          acc += wgt[0][kx] * fr0[w + kx];
          acc += wgt[1][kx] * fr1[w + kx];
          acc += wgt[2][kx] * fr2[w + kx];
        }
        sT[(h * 16 + w) * 136 + c] = f2bf_s(acc * scale + shift);
      }
    }
  }
  __syncthreads();

  // ---- drop prefetched weights into sY region ----
  {
    uint4* wdst = (uint4*)pw_lds;
    wdst[tid] = pf0; wdst[tid + 512] = pf1; wdst[tid + 1024] = pf2;
    wdst[tid + 1536] = pf3; wdst[tid + 2048] = pf4;
    if (tid < 160) wdst[tid + 2560] = pf5;
  }
  __syncthreads();

  // ---- fpw MFMA: r[o=128][pos=256], K=128; wave tile 64x64 ----
  int o0 = (wid & 1) * 64, pos0 = (wid >> 1) * 64;
  f32x4 acc[4][4] = {};
#pragma unroll
  for (int kk = 0; kk < 4; kk++) {
    int k0 = kk * 32 + kg * 8;
    short8v a[4], bb[4];
#pragma unroll
    for (int mi = 0; mi < 4; mi++)
      a[mi] = *(const short8v*)&pw_lds[(o0 + mi * 16 + row) * 136 + k0];
#pragma unroll
    for (int ni = 0; ni < 4; ni++)
      bb[ni] = *(const short8v*)&sT[(pos0 + ni * 16 + row) * 136 + k0];
#pragma unroll
    for (int mi = 0; mi < 4; mi++)
#pragma unroll
      for (int ni = 0; ni < 4; ni++)
        acc[mi][ni] = __builtin_amdgcn_mfma_f32_16x16x32_bf16(a[mi], bb[ni], acc[mi][ni], 0, 0, 0);
  }
  __syncthreads();

  // ---- bias + ReLU -> sT[pos][o] (overwrite) ----
#pragma unroll
  for (int mi = 0; mi < 4; mi++) {
    int obase = o0 + mi * 16 + kg * 4;
    float pb0 = pwb[obase], pb1 = pwb[obase + 1], pb2 = pwb[obase + 2], pb3 = pwb[obase + 3];
#pragma unroll
    for (int ni = 0; ni < 4; ni++) {
      int pos = pos0 + ni * 16 + row;
      short4v pk;
      pk.x = f2bf_s(fmaxf(acc[mi][ni][0] + pb0, 0.f));
      pk.y = f2bf_s(fmaxf(acc[mi][ni][1] + pb1, 0.f));
      pk.z = f2bf_s(fmaxf(acc[mi][ni][2] + pb2, 0.f));
      pk.w = f2bf_s(fmaxf(acc[mi][ni][3] + pb3, 0.f));
      *(short4v*)&sT[pos * 136 + obase] = pk;
    }
  }
  __syncthreads();

  // ---- f2 MFMA: out[d=32][pos=256], K=128 ----
  {
    f32x4 acc2[2][2] = {};
    int nbase = wid * 2;
#pragma unroll
    for (int kk = 0; kk < 4; kk++) {
      int k0 = kk * 32 + kg * 8;
      short8v a2[2], b2[2];
#pragma unroll
      for (int mi = 0; mi < 2; mi++)
        a2[mi] = *(const short8v*)&f2w_lds[(mi * 16 + row) * 136 + k0];
#pragma unroll
      for (int ni = 0; ni < 2; ni++)
        b2[ni] = *(const short8v*)&sT[((nbase + ni) * 16 + row) * 136 + k0];
#pragma unroll
      for (int mi = 0; mi < 2; mi++)
#pragma unroll
        for (int ni = 0; ni < 2; ni++)
          acc2[mi][ni] = __builtin_amdgcn_mfma_f32_16x16x32_bf16(a2[mi], b2[ni], acc2[mi][ni], 0, 0, 0);
    }
#pragma unroll
    for (int mi = 0; mi < 2; mi++)
#pragma unroll
      for (int ni = 0; ni < 2; ni++) {
        int pos = (nbase + ni) * 16 + row;
        int dbase = mi * 16 + kg * 4;
        f2out[(dbase + 0) * 257 + pos] = acc2[mi][ni][0];
        f2out[(dbase + 1) * 257 + pos] = acc2[mi][ni][1];
        f2out[(dbase + 2) * 257 + pos] = acc2[mi][ni][2];
        f2out[(dbase + 3) * 257 + pos] = acc2[mi][ni][3];
      }
  }
  __syncthreads();

  // ---- residual epilogue (coalesced) ----
  float* xo = xg + (size_t)b * 8192;
#pragma unroll
  for (int j = 0; j < 16; j++) {
    int idx = tid + j * 512;
    int dm = idx & 511;
    int d = dm >> 4, p2 = dm & 15;
    int p1 = idx >> 9;
    xo[idx] += f2out[d * 257 + p1 * 16 + p2] + f2b[d];
  }
}

extern "C" void kernel_launch(void* const* d_in, const int* in_sizes, int n_in,
                              void* d_out, int out_size, void* d_ws, size_t ws_size,
                              hipStream_t stream) {
  const float* x_in   = (const float*)d_in[0];
  const float* ln1_g  = (const float*)d_in[1];
  const float* ln1_b  = (const float*)d_in[2];
  const float* ln2_g  = (const float*)d_in[3];
  const float* ln2_b  = (const float*)d_in[4];
  const float* qkv_dw = (const float*)d_in[5];
  const float* qkv_bng = (const float*)d_in[6];
  const float* qkv_bnb = (const float*)d_in[7];
  const float* qkv_bnm = (const float*)d_in[8];
  const float* qkv_bnv = (const float*)d_in[9];
  const float* qkv_pw = (const float*)d_in[10];
  const float* position = (const float*)d_in[11];
  const float* c1d_w  = (const float*)d_in[12];
  const float* c1d_b  = (const float*)d_in[13];
  const float* lin_w  = (const float*)d_in[14];
  const float* lin_b  = (const float*)d_in[15];
  const float* f1_w   = (const float*)d_in[16];
  const float* f1_b   = (const float*)d_in[17];
  const float* fdw_w  = (const float*)d_in[18];
  const float* fdw_b  = (const float*)d_in[19];
  const float* f_bng  = (const float*)d_in[20];
  const float* f_bnb  = (const float*)d_in[21];
  const float* f_bnm  = (const float*)d_in[22];
  const float* f_bnv  = (const float*)d_in[23];
  const float* fpw_w  = (const float*)d_in[24];
  const float* fpw_b  = (const float*)d_in[25];
  const float* f2_w   = (const float*)d_in[26];
  const float* f2_b   = (const float*)d_in[27];

  float* xbuf = (float*)d_out;                 // running x lives in d_out
  short* f1wb = (short*)d_ws;                  // 10240
  short* img  = f1wb + 10240;                  // 43520
  short* qkvA = img + 43520;                   // 7680
  short* linb = qkvA + 7680;                   // 262144

  hipMemcpyAsync(xbuf, x_in, (size_t)B_ * 8192 * sizeof(float),
                 hipMemcpyDeviceToDevice, stream);
  k_prep<<<1024, 256, 0, stream>>>(f1_w, fpw_w, f2_w, qkv_pw, lin_w,
                                   f1wb, img, qkvA, linb);
  for (int l = 0; l < 2; l++) {
    k_att<<<B_, 256, 0, stream>>>(xbuf, ln1_g + l * 512, ln1_b + l * 512,
        qkv_dw + l * 864, qkv_bng + l * 96, qkv_bnb + l * 96,
        qkv_bnm + l * 96, qkv_bnv + l * 96, qkvA + l * 3840,
        position + l * 1024, c1d_w + l * 128, c1d_b + l * 16,
        linb + l * 131072, lin_b + l * 512, xbuf);
    k_ffn2<<<B_, 512, 0, stream>>>(xbuf, ln2_g + l * 512, ln2_b + l * 512,
        f1wb + l * 5120, f1_b + l * 128, fdw_w + l * 1152, fdw_b + l * 128,
        f_bng + l * 128, f_bnb + l * 128, f_bnm + l * 128, f_bnv + l * 128,
        img + l * 21760, fpw_b + l * 128, f2_b + l * 32, xbuf);
  }
}